// Round 2
// baseline (1007.956 us; speedup 1.0000x reference)
//
#include <hip/hip_runtime.h>

#define HH 50
#define TT 1024
#define BT 16             // batch tile per MFMA (M)
#define NTILE 2           // independent tiles per block (stall amortization)
#define NB (2048 / (BT * NTILE))   // 64 blocks
#define CHUNK 256         // x staging chunk (timesteps)
#define XST 260           // x LDS row stride (floats)
#define HST 72            // h LDS row stride (f16 elems)

typedef _Float16 half8 __attribute__((ext_vector_type(8)));
typedef float f32x4 __attribute__((ext_vector_type(4)));

union H8 { half8 v; _Float16 h[8]; unsigned short u[8]; unsigned int i[4]; };

__device__ __forceinline__ float rcp_f(float x) { return __builtin_amdgcn_rcpf(x); }

#if __has_builtin(__builtin_amdgcn_exp2f)
__device__ __forceinline__ float exp2_f(float x) { return __builtin_amdgcn_exp2f(x); }
#else
__device__ __forceinline__ float exp2_f(float x) { return __expf(0.6931471805599453f * x); }
#endif

#define L2E   1.4426950408889634f
#define L2E2  2.8853900817779268f

// weights pre-scaled: i,f,o rows by -log2e; g rows by +2*log2e
__device__ __forceinline__ float sigm_n(float a) {   // sigmoid(x), a = -x*log2e
    return rcp_f(1.0f + exp2_f(a));
}
__device__ __forceinline__ float tanh_p(float a) {   // tanh(x), a = 2x*log2e
    return __builtin_fmaf(-2.0f, rcp_f(1.0f + exp2_f(a)), 1.0f);
}
__device__ __forceinline__ unsigned short f2h(float f) {
    return __builtin_bit_cast(unsigned short, (_Float16)f);
}

__global__ __launch_bounds__(512, 2) void lstm_mfma_kernel(
    const float* __restrict__ x,
    const float* __restrict__ wih1, const float* __restrict__ whh1,
    const float* __restrict__ bih1, const float* __restrict__ bhh1,
    const float* __restrict__ wih2,
    const float* __restrict__ bih2, const float* __restrict__ bhh2,
    const float* __restrict__ fcw,  const float* __restrict__ fcb,
    float* __restrict__ out)
{
    __shared__ float xs[NTILE][BT * XST];                        // 33.3 KB
    __shared__ __align__(16) unsigned short hb[NTILE][2][BT * HST]; // 9.2 KB
    __shared__ float h2s[NTILE][BT * 52];                        // 6.7 KB

    const int tid  = threadIdx.x;
    const int wv   = tid >> 6;        // 0..7
    const int js   = wv & 3;          // j-slice 0..3
    const int bh   = wv >> 2;         // batch-half (and LSTM2 tile) 0..1
    const int lane = tid & 63;
    const int l16  = lane & 15;
    const int quad = lane >> 4;
    const int j    = js * 16 + l16;   // padded gate sub-index 0..63
    const bool jv  = (j < HH);
    const bool q2  = (quad == 2);
    const int b0   = blockIdx.x * (BT * NTILE);

    // ---- persistent per-lane weights: Whh B-frags (f16, gate-folded scale) ----
    // K layout: k=0..49 Whh; k=50 <- Wih (x slot); k=51 <- bias_hi; k=52 <- bias_lo
    // SHARED by both tiles.
    H8 bw[4][2];
    #pragma unroll
    for (int t4 = 0; t4 < 4; ++t4) {
        const float sc = (t4 == 2) ? L2E2 : -L2E;
        const int row = t4 * HH + j;
        #pragma unroll
        for (int kk = 0; kk < 2; ++kk)
            #pragma unroll
            for (int e = 0; e < 8; ++e) {
                const int k = kk * 32 + quad * 8 + e;
                const float v = (jv && k < HH) ? whh1[row * HH + k] * sc : 0.0f;
                bw[t4][kk].h[e] = (_Float16)v;
            }
        if (q2) {
            const float bsc = jv ? (bih1[row] + bhh1[row]) * sc : 0.0f;
            const _Float16 bhi = (_Float16)bsc;
            bw[t4][1].h[2] = (_Float16)(jv ? wih1[row] * sc : 0.0f); // k=50
            bw[t4][1].h[3] = bhi;                                    // k=51
            bw[t4][1].h[4] = (_Float16)(bsc - (float)bhi);           // k=52
        }
    }

    // zero initial h buffers (both tiles, buf 0; zeroing all is simplest)
    for (int i = tid; i < NTILE * 2 * BT * HST; i += 512)
        ((unsigned short*)hb)[i] = 0;

    float cA0 = 0.f, cA1 = 0.f, cB0 = 0.f, cB1 = 0.f;
    unsigned short* curA = hb[0][0]; unsigned short* nxtA = hb[0][1];
    unsigned short* curB = hb[1][0]; unsigned short* nxtB = hb[1][1];
    const f32x4 kZ = {0.f, 0.f, 0.f, 0.f};
    const int r0 = bh * 2;            // this wave's accumulator rows r0, r0+1
    float xvA = 0.f, xvB = 0.f;

    for (int t = 0; t < TT; ++t) {
        const int tc = t & (CHUNK - 1);
        if (tc == 0) {
            for (int i = tid; i < NTILE * BT * (CHUNK / 4); i += 512) {
                const int tl = i >> 10;               // BT*CHUNK/4 = 1024 per tile
                const int r  = (i >> 6) & (BT - 1), c4 = i & 63;
                const float4 q = ((const float4*)x)[((b0 + tl * BT + r) * TT + t) / 4 + c4];
                *(float4*)&xs[tl][r * XST + c4 * 4] = q;
            }
            __syncthreads();          // also covers hb zeroing at t==0
            xvA = xs[0][l16 * XST];   // reload after restage
            xvB = xs[1][l16 * XST];
        }

        // ---- issue both tiles' LDS reads up front ----
        H8 a0A, a1A, a0B, a1B;
        a0A.v = *(const half8*)&curA[l16 * HST + quad * 8];
        a1A.v = *(const half8*)&curA[l16 * HST + 32 + quad * 8];
        a0B.v = *(const half8*)&curB[l16 * HST + quad * 8];
        a1B.v = *(const half8*)&curB[l16 * HST + 32 + quad * 8];

        // A-frag patch words: (x_t|1.0) at k=50,51 and (1.0|0) at k=52,53
        const unsigned int pkA = 0x3c000000u | (unsigned int)f2h(xvA);
        const unsigned int pkB = 0x3c000000u | (unsigned int)f2h(xvB);
        a1A.i[1] = q2 ? pkA : a1A.i[1];
        a1A.i[2] = q2 ? 0x00003c00u : a1A.i[2];
        a1B.i[1] = q2 ? pkB : a1B.i[1];
        a1B.i[2] = q2 ? 0x00003c00u : a1B.i[2];

        f32x4 accA[4], accB[4];
        #pragma unroll
        for (int t4 = 0; t4 < 4; ++t4) {
            accA[t4] = __builtin_amdgcn_mfma_f32_16x16x32_f16(a0A.v, bw[t4][0].v, kZ, 0, 0, 0);
            accA[t4] = __builtin_amdgcn_mfma_f32_16x16x32_f16(a1A.v, bw[t4][1].v, accA[t4], 0, 0, 0);
        }
        #pragma unroll
        for (int t4 = 0; t4 < 4; ++t4) {
            accB[t4] = __builtin_amdgcn_mfma_f32_16x16x32_f16(a0B.v, bw[t4][0].v, kZ, 0, 0, 0);
            accB[t4] = __builtin_amdgcn_mfma_f32_16x16x32_f16(a1B.v, bw[t4][1].v, accB[t4], 0, 0, 0);
        }

        // prefetch next-step x (off critical path; stale at chunk end, reloaded above)
        xvA = xs[0][l16 * XST + ((tc + 1) & (CHUNK - 1))];
        xvB = xs[1][l16 * XST + ((tc + 1) & (CHUNK - 1))];

        // ---- gate math, tile A (2 rows) ----
        {
            const float ig = sigm_n(accA[0][r0]);
            const float fg = sigm_n(accA[1][r0]);
            const float gg = tanh_p(accA[2][r0]);
            const float og = sigm_n(accA[3][r0]);
            cA0 = __builtin_fmaf(fg, cA0, ig * gg);
            nxtA[(quad * 4 + r0) * HST + j] = f2h(og * tanh_p(cA0 * L2E2));
        }
        {
            const float ig = sigm_n(accA[0][r0 + 1]);
            const float fg = sigm_n(accA[1][r0 + 1]);
            const float gg = tanh_p(accA[2][r0 + 1]);
            const float og = sigm_n(accA[3][r0 + 1]);
            cA1 = __builtin_fmaf(fg, cA1, ig * gg);
            nxtA[(quad * 4 + r0 + 1) * HST + j] = f2h(og * tanh_p(cA1 * L2E2));
        }
        // ---- gate math, tile B (2 rows) ----
        {
            const float ig = sigm_n(accB[0][r0]);
            const float fg = sigm_n(accB[1][r0]);
            const float gg = tanh_p(accB[2][r0]);
            const float og = sigm_n(accB[3][r0]);
            cB0 = __builtin_fmaf(fg, cB0, ig * gg);
            nxtB[(quad * 4 + r0) * HST + j] = f2h(og * tanh_p(cB0 * L2E2));
        }
        {
            const float ig = sigm_n(accB[0][r0 + 1]);
            const float fg = sigm_n(accB[1][r0 + 1]);
            const float gg = tanh_p(accB[2][r0 + 1]);
            const float og = sigm_n(accB[3][r0 + 1]);
            cB1 = __builtin_fmaf(fg, cB1, ig * gg);
            nxtB[(quad * 4 + r0 + 1) * HST + j] = f2h(og * tanh_p(cB1 * L2E2));
        }

        unsigned short* tmp;
        tmp = curA; curA = nxtA; nxtA = tmp;
        tmp = curB; curB = nxtB; nxtB = tmp;
        __syncthreads();              // ONE barrier per 2 tile-steps
    }

    // ---- LSTM2: one cell step from zero state; bh picks the tile ----
    {
        const unsigned short* curT = bh ? curB : curA;
        H8 bw2[4][2];
        float b2[4];
        #pragma unroll
        for (int t4 = 0; t4 < 4; ++t4) {
            const float sc = (t4 == 2) ? L2E2 : -L2E;
            const int row = t4 * HH + j;
            #pragma unroll
            for (int kk = 0; kk < 2; ++kk)
                #pragma unroll
                for (int e = 0; e < 8; ++e) {
                    const int k = kk * 32 + quad * 8 + e;
                    const float v = (jv && k < HH) ? wih2[row * HH + k] * sc : 0.0f;
                    bw2[t4][kk].h[e] = (_Float16)v;
                }
            b2[t4] = jv ? (bih2[row] + bhh2[row]) * sc : 0.0f;
        }
        H8 a0, a1;
        a0.v = *(const half8*)&curT[l16 * HST + quad * 8];
        a1.v = *(const half8*)&curT[l16 * HST + 32 + quad * 8];
        f32x4 acc2[4];
        #pragma unroll
        for (int t4 = 0; t4 < 4; ++t4) {
            const f32x4 cb = {b2[t4], b2[t4], b2[t4], b2[t4]};
            acc2[t4] = __builtin_amdgcn_mfma_f32_16x16x32_f16(a0.v, bw2[t4][0].v, cb, 0, 0, 0);
            acc2[t4] = __builtin_amdgcn_mfma_f32_16x16x32_f16(a1.v, bw2[t4][1].v, acc2[t4], 0, 0, 0);
        }
        #pragma unroll
        for (int r = 0; r < 4; ++r) {
            const float ig = sigm_n(acc2[0][r]);
            const float gg = tanh_p(acc2[2][r]);
            const float og = sigm_n(acc2[3][r]);
            const float cc = ig * gg;            // f*c0 term vanishes (c0 = 0)
            const float h2 = og * tanh_p(cc * L2E2);
            if (jv) h2s[bh][(quad * 4 + r) * 52 + j] = h2;
        }
    }
    __syncthreads();

    // ---- FC: out[b] = h2[b] . fcW + fcb  (32 batches, 512 threads) ----
    {
        const int b = tid >> 4, l = tid & 15;    // b 0..31: tile = b>>4, row = b&15
        float p = 0.f;
        for (int jj = l; jj < HH; jj += 16)
            p = __builtin_fmaf(h2s[b >> 4][(b & 15) * 52 + jj], fcw[jj], p);
        #pragma unroll
        for (int off = 8; off > 0; off >>= 1) p += __shfl_xor(p, off, 16);
        if (l == 0) out[b0 + b] = p + fcb[0];
    }
}

extern "C" void kernel_launch(void* const* d_in, const int* in_sizes, int n_in,
                              void* d_out, int out_size, void* d_ws, size_t ws_size,
                              hipStream_t stream) {
    lstm_mfma_kernel<<<NB, 512, 0, stream>>>(
        (const float*)d_in[0],                         // x
        (const float*)d_in[1], (const float*)d_in[2],  // lstm1 Wih, Whh
        (const float*)d_in[3], (const float*)d_in[4],  // lstm1 bih, bhh
        (const float*)d_in[5],                         // lstm2 Wih
        (const float*)d_in[7], (const float*)d_in[8],  // lstm2 bih, bhh
        (const float*)d_in[9], (const float*)d_in[10], // fc W, b
        (float*)d_out);
}

// Round 4
// 606.012 us; speedup vs baseline: 1.6633x; 1.6633x over previous
//
#include <hip/hip_runtime.h>

#define HH 50
#define TT 1024
#define BT 16            // batch tile per block (MFMA M)
#define NB (2048 / BT)   // 128 blocks
#define CHUNK 256        // x staging chunk (timesteps)
#define XST 260          // x LDS row stride (floats)
#define HST 72           // h LDS row stride (f16 elems)

typedef _Float16 half8 __attribute__((ext_vector_type(8)));
typedef float f32x4 __attribute__((ext_vector_type(4)));

union H8 { half8 v; _Float16 h[8]; unsigned short u[8]; unsigned int i[4]; };

__device__ __forceinline__ float rcp_f(float x) { return __builtin_amdgcn_rcpf(x); }

#if __has_builtin(__builtin_amdgcn_exp2f)
__device__ __forceinline__ float exp2_f(float x) { return __builtin_amdgcn_exp2f(x); }
#else
__device__ __forceinline__ float exp2_f(float x) { return __expf(0.6931471805599453f * x); }
#endif

#define L2E   1.4426950408889634f
#define L2E2  2.8853900817779268f

// weights pre-scaled: i,f,o rows by -log2e; g rows by +2*log2e
__device__ __forceinline__ float sigm_n(float a) {   // sigmoid(x), a = -x*log2e
    return rcp_f(1.0f + exp2_f(a));
}
__device__ __forceinline__ float tanh_p(float a) {   // tanh(x), a = 2x*log2e
    return __builtin_fmaf(-2.0f, rcp_f(1.0f + exp2_f(a)), 1.0f);
}
__device__ __forceinline__ unsigned short f2h(float f) {
    return __builtin_bit_cast(unsigned short, (_Float16)f);
}

__global__ __launch_bounds__(512) void lstm_mfma_kernel(
    const float* __restrict__ x,
    const float* __restrict__ wih1, const float* __restrict__ whh1,
    const float* __restrict__ bih1, const float* __restrict__ bhh1,
    const float* __restrict__ wih2,
    const float* __restrict__ bih2, const float* __restrict__ bhh2,
    const float* __restrict__ fcw,  const float* __restrict__ fcb,
    float* __restrict__ out)
{
    __shared__ float xs[BT * XST];                       // 16.6 KB
    __shared__ __align__(16) unsigned short hb[2][BT * HST]; // 4.6 KB (f16 bits)
    __shared__ float h2s[BT * 52];                       // 3.3 KB

    const int tid  = threadIdx.x;
    const int wv   = tid >> 6;        // 0..7
    const int js   = wv & 3;          // j-slice 0..3
    const int bh   = wv >> 2;         // batch half 0..1
    const int lane = tid & 63;
    const int l16  = lane & 15;
    const int quad = lane >> 4;
    const int j    = js * 16 + l16;   // padded gate sub-index 0..63
    const bool jv  = (j < HH);
    const bool q2  = (quad == 2);
    const int b0   = blockIdx.x * BT;

    // ---- persistent per-lane weights: Whh B-frags (f16, gate-folded scale) ----
    // K layout: k=0..49 Whh; k=50 <- Wih (x slot); k=51 <- bias_hi; k=52 <- bias_lo
    H8 bw[4][2];
    #pragma unroll
    for (int t4 = 0; t4 < 4; ++t4) {
        const float sc = (t4 == 2) ? L2E2 : -L2E;
        const int row = t4 * HH + j;
        #pragma unroll
        for (int kk = 0; kk < 2; ++kk)
            #pragma unroll
            for (int e = 0; e < 8; ++e) {
                const int k = kk * 32 + quad * 8 + e;
                const float v = (jv && k < HH) ? whh1[row * HH + k] * sc : 0.0f;
                bw[t4][kk].h[e] = (_Float16)v;
            }
        if (q2) {
            const float bsc = jv ? (bih1[row] + bhh1[row]) * sc : 0.0f;
            const _Float16 bhi = (_Float16)bsc;
            bw[t4][1].h[2] = (_Float16)(jv ? wih1[row] * sc : 0.0f); // k=50
            bw[t4][1].h[3] = bhi;                                    // k=51
            bw[t4][1].h[4] = (_Float16)(bsc - (float)bhi);           // k=52
        }
    }

    // zero h buffers with 1.0 planted at A-slots k=51,52 (race-free: single pass)
    for (int i = tid; i < 2 * BT * HST; i += 512) {
        const int col = i % HST;
        ((unsigned short*)hb)[i] = (col == 51 || col == 52) ? 0x3c00 : 0;
    }

    float c0 = 0.f, c1 = 0.f;
    const f32x4 kZ = {0.f, 0.f, 0.f, 0.f};
    const int r0 = bh * 2;                 // this wave's accumulator rows r0, r0+1
    const bool xw = (wv == 0) && (lane < 16);   // x-slot writer lanes (row = lane)

    // fused cell: 7 trans (5 exp2 + 2 rcp) instead of 10
    // c' = [c*(1+Ei)(1+Eg) + (Eg-1)(1+Ef)] / [(1+Ef)(1+Ei)(1+Eg)]
    // h  = (Ec-1) / [(1+Eo)(1+Ec)],  Ec = exp2(min(c'*2log2e, 80))
    auto cell = [&](float ai, float af, float ag, float ao, float& c) -> unsigned short {
        const float Ei = exp2_f(ai), Ef = exp2_f(af), Eg = exp2_f(ag), Eo = exp2_f(ao);
        const float pf  = 1.0f + Ef;
        const float P   = (1.0f + Ei) * (1.0f + Eg);
        const float den = pf * P;
        const float num = __builtin_fmaf(c, P, (Eg - 1.0f) * pf);
        c = num * rcp_f(den);
        const float ac = fminf(c * L2E2, 80.0f);   // upper clamp only; Ec->0 is graceful
        const float Ec = exp2_f(ac);
        const float h  = (Ec - 1.0f) * rcp_f((1.0f + Eo) * (1.0f + Ec));
        return f2h(h);
    };

#define STEP(T, CUR, NXT, STAGEOK)                                                     \
    {                                                                                  \
        const int tc = (T) & (CHUNK - 1);                                              \
        if (STAGEOK && tc == 0) {                                                      \
            for (int i = tid; i < BT * (CHUNK / 4); i += 512) {                        \
                const int r = i >> 6, c4 = i & 63;                                     \
                const float4 q = ((const float4*)x)[((b0 + r) * TT + (T)) / 4 + c4];   \
                *(float4*)&xs[r * XST + c4 * 4] = q;                                   \
            }                                                                          \
            __syncthreads();   /* also covers hb zero/plant at t==0 */                 \
        }                                                                              \
        H8 a0, a1;                                                                     \
        a0.v = *(const half8*)&(CUR)[l16 * HST + quad * 8];                            \
        a1.v = *(const half8*)&(CUR)[l16 * HST + 32 + quad * 8];                       \
        if (STAGEOK && tc == 0) {                                                      \
            /* chunk-boundary: LDS x-slot is stale; patch regs (uniform, 4/1024) */    \
            const float xv = xs[l16 * XST];                                            \
            const unsigned int pk = 0x3c000000u | (unsigned int)f2h(xv);               \
            a1.i[1] = q2 ? pk : a1.i[1];                                               \
            a1.i[2] = q2 ? 0x00003c00u : a1.i[2];                                      \
        }                                                                              \
        float xnext = 0.0f;                                                            \
        if (xw) xnext = xs[lane * XST + ((tc + 1) & (CHUNK - 1))];                     \
        f32x4 acc[4];                                                                  \
        _Pragma("unroll")                                                              \
        for (int t4 = 0; t4 < 4; ++t4) {                                               \
            acc[t4] = __builtin_amdgcn_mfma_f32_16x16x32_f16(a0.v, bw[t4][0].v, kZ, 0, 0, 0);       \
            acc[t4] = __builtin_amdgcn_mfma_f32_16x16x32_f16(a1.v, bw[t4][1].v, acc[t4], 0, 0, 0);  \
        }                                                                              \
        const unsigned short h0 =                                                      \
            cell(acc[0][r0], acc[1][r0], acc[2][r0], acc[3][r0], c0);                  \
        const unsigned short h1 =                                                      \
            cell(acc[0][r0 + 1], acc[1][r0 + 1], acc[2][r0 + 1], acc[3][r0 + 1], c1);  \
        if (jv) {   /* j>=50 lanes must NOT clobber the planted k=50..52 slots */      \
            (NXT)[(quad * 4 + r0) * HST + j]     = h0;                                 \
            (NXT)[(quad * 4 + r0 + 1) * HST + j] = h1;                                 \
        }                                                                              \
        if (xw) (NXT)[lane * HST + 50] = f2h(xnext);  /* stale at chunk end: patched */\
        __syncthreads();                                                               \
    }

    for (int t = 0; t < TT; t += 2) {
        STEP(t,     hb[0], hb[1], true);
        STEP(t + 1, hb[1], hb[0], false);
    }
#undef STEP
    // final h1 is in hb[0]
    unsigned short* cur = hb[0];

    // ---- LSTM2: one cell step from zero state, input = h1 ----
    {
        H8 bw2[4][2];
        float b2[4];
        #pragma unroll
        for (int t4 = 0; t4 < 4; ++t4) {
            const float sc = (t4 == 2) ? L2E2 : -L2E;
            const int row = t4 * HH + j;
            #pragma unroll
            for (int kk = 0; kk < 2; ++kk)
                #pragma unroll
                for (int e = 0; e < 8; ++e) {
                    const int k = kk * 32 + quad * 8 + e;
                    const float v = (jv && k < HH) ? wih2[row * HH + k] * sc : 0.0f;
                    bw2[t4][kk].h[e] = (_Float16)v;
                }
            b2[t4] = jv ? (bih2[row] + bhh2[row]) * sc : 0.0f;
        }
        // a1 reads k=50..52 slots too, but bw2 is zero there -> harmless
        H8 a0, a1;
        a0.v = *(const half8*)&cur[l16 * HST + quad * 8];
        a1.v = *(const half8*)&cur[l16 * HST + 32 + quad * 8];
        f32x4 acc2[4];
        #pragma unroll
        for (int t4 = 0; t4 < 4; ++t4) {
            const f32x4 cb = {b2[t4], b2[t4], b2[t4], b2[t4]};
            acc2[t4] = __builtin_amdgcn_mfma_f32_16x16x32_f16(a0.v, bw2[t4][0].v, cb, 0, 0, 0);
            acc2[t4] = __builtin_amdgcn_mfma_f32_16x16x32_f16(a1.v, bw2[t4][1].v, acc2[t4], 0, 0, 0);
        }
        #pragma unroll
        for (int r = 0; r < 4; ++r) {
            const float ig = sigm_n(acc2[0][r]);
            const float gg = tanh_p(acc2[2][r]);
            const float og = sigm_n(acc2[3][r]);
            const float cc = ig * gg;            // f*c0 term vanishes (c0 = 0)
            const float h2 = og * tanh_p(cc * L2E2);
            if (jv) h2s[(quad * 4 + r) * 52 + j] = h2;
        }
    }
    __syncthreads();

    // ---- FC: out[b] = h2[b] . fcW + fcb ----
    if (tid < 256) {
        const int b = tid >> 4, l = tid & 15;
        float p = 0.f;
        for (int jj = l; jj < HH; jj += 16)
            p = __builtin_fmaf(h2s[b * 52 + jj], fcw[jj], p);
        #pragma unroll
        for (int off = 8; off > 0; off >>= 1) p += __shfl_xor(p, off, 16);
        if (l == 0) out[b0 + b] = p + fcb[0];
    }
}

extern "C" void kernel_launch(void* const* d_in, const int* in_sizes, int n_in,
                              void* d_out, int out_size, void* d_ws, size_t ws_size,
                              hipStream_t stream) {
    lstm_mfma_kernel<<<NB, 512, 0, stream>>>(
        (const float*)d_in[0],                         // x
        (const float*)d_in[1], (const float*)d_in[2],  // lstm1 Wih, Whh
        (const float*)d_in[3], (const float*)d_in[4],  // lstm1 bih, bhh
        (const float*)d_in[5],                         // lstm2 Wih
        (const float*)d_in[7], (const float*)d_in[8],  // lstm2 bih, bhh
        (const float*)d_in[9], (const float*)d_in[10], // fc W, b
        (float*)d_out);
}

// Round 6
// 516.828 us; speedup vs baseline: 1.9503x; 1.1726x over previous
//
#include <hip/hip_runtime.h>

#define HH 50
#define TT 1024
#define BT 8             // batch tile per block (half an MFMA M)
#define NB (2048 / BT)   // 256 blocks -> 1 per CU, all CUs active
#define CHUNK 256        // x staging chunk (timesteps)
#define XST 260          // x LDS row stride (floats)
#define HST 72           // h LDS row stride (f16 elems)

typedef _Float16 half8 __attribute__((ext_vector_type(8)));
typedef float f32x4 __attribute__((ext_vector_type(4)));

union H8 { half8 v; _Float16 h[8]; unsigned short u[8]; unsigned int i[4]; };

__device__ __forceinline__ float rcp_f(float x) { return __builtin_amdgcn_rcpf(x); }

#if __has_builtin(__builtin_amdgcn_exp2f)
__device__ __forceinline__ float exp2_f(float x) { return __builtin_amdgcn_exp2f(x); }
#else
__device__ __forceinline__ float exp2_f(float x) { return __expf(0.6931471805599453f * x); }
#endif

#define L2E   1.4426950408889634f
#define L2E2  2.8853900817779268f

__device__ __forceinline__ float sigm_n(float a) {   // sigmoid(x), a = -x*log2e
    return rcp_f(1.0f + exp2_f(a));
}
__device__ __forceinline__ float tanh_p(float a) {   // tanh(x), a = 2x*log2e
    return __builtin_fmaf(-2.0f, rcp_f(1.0f + exp2_f(a)), 1.0f);
}
__device__ __forceinline__ unsigned short f2h(float f) {
    return __builtin_bit_cast(unsigned short, (_Float16)f);
}
__device__ __forceinline__ float bperm(int addr, float v) {
    return __builtin_bit_cast(float,
        __builtin_amdgcn_ds_bpermute(addr, __builtin_bit_cast(int, v)));
}

__global__ __launch_bounds__(512) void lstm_mfma_kernel(
    const float* __restrict__ x,
    const float* __restrict__ wih1, const float* __restrict__ whh1,
    const float* __restrict__ bih1, const float* __restrict__ bhh1,
    const float* __restrict__ wih2,
    const float* __restrict__ bih2, const float* __restrict__ bhh2,
    const float* __restrict__ fcw,  const float* __restrict__ fcb,
    float* __restrict__ out)
{
    __shared__ float xs[BT * XST];                           // 8.3 KB
    __shared__ __align__(16) unsigned short hb[2][16 * HST]; // 4.6 KB (rows 8-15 stay 0)
    __shared__ float h2s[BT * 52];                           // 1.7 KB

    const int tid  = threadIdx.x;
    const int wv   = tid >> 6;        // 0..7
    const int js   = wv & 3;          // j-slice 0..3
    const int bh   = wv >> 2;         // cell-parity 0..1 (MFMAs duplicated across bh)
    const int lane = tid & 63;
    const int l16  = lane & 15;
    const int quad = lane >> 4;
    const int j    = js * 16 + l16;   // padded gate sub-index 0..63
    const bool jv  = (j < HH);
    const bool q2  = (quad == 2);
    const int b0   = blockIdx.x * BT;
    // 1-cell-per-lane redistribution. D layout: row=(lane>>4)*4+reg, col=lane&15.
    // Lane (quad,l16) of wave bh owns batch bmine = quad*2+bh at column l16.
    // Row b lives at src lane (b>>2)*16+l16, reg b&3.  ds_bpermute payloads are
    // evaluated IN THE SOURCE LANE, so two payloads per gate:
    //   v1 = qodd_src ? e02 : e00   (delivers rows  bh  from srcq0, 6+bh from srcq1)
    //   v2 = qodd_src ? e00 : e02   (delivers rows 2+bh from srcq0, 4+bh from srcq1)
    // with e00 = acc[bh], e02 = acc[2+bh].  Dest: quads {0,3} take bp1, {1,2} take bp2.
    const int  srcl  = ((quad >> 1) * 16 + l16) * 4;  // bpermute byte addr
    const bool qodd  = (quad & 1);
    const bool useb1 = (((quad ^ (quad >> 1)) & 1) == 0);   // quads 0,3
    const int  bmine = quad * 2 + bh;                 // 0..7

    // ---- persistent per-lane weights: Whh B-frags (f16, gate-folded scale) ----
    // K layout: k=0..49 Whh; k=50 <- Wih (x slot); k=51 <- bias_hi; k=52 <- bias_lo
    H8 bw[4][2];
    #pragma unroll
    for (int t4 = 0; t4 < 4; ++t4) {
        const float sc = (t4 == 2) ? L2E2 : -L2E;
        const int row = t4 * HH + j;
        #pragma unroll
        for (int kk = 0; kk < 2; ++kk)
            #pragma unroll
            for (int e = 0; e < 8; ++e) {
                const int k = kk * 32 + quad * 8 + e;
                const float v = (jv && k < HH) ? whh1[row * HH + k] * sc : 0.0f;
                bw[t4][kk].h[e] = (_Float16)v;
            }
        if (q2) {
            const float bsc = jv ? (bih1[row] + bhh1[row]) * sc : 0.0f;
            const _Float16 bhi = (_Float16)bsc;
            bw[t4][1].h[2] = (_Float16)(jv ? wih1[row] * sc : 0.0f); // k=50
            bw[t4][1].h[3] = bhi;                                    // k=51
            bw[t4][1].h[4] = (_Float16)(bsc - (float)bhi);           // k=52
        }
    }

    // zero h buffers with 1.0 planted at A-slots k=51,52 (race-free single pass)
    for (int i = tid; i < 2 * 16 * HST; i += 512) {
        const int col = i % HST;
        ((unsigned short*)hb)[i] = (col == 51 || col == 52) ? 0x3c00 : 0;
    }

    float c = 0.f;                       // one cell per lane
    const f32x4 kZ = {0.f, 0.f, 0.f, 0.f};
    const bool xw = (wv == 0) && (lane < BT);   // x-slot writer lanes (row = lane)

    // fused cell: 7 trans (5 exp2 + 2 rcp)
    auto cell = [&](float ai, float af, float ag, float ao, float& cc) -> unsigned short {
        const float Ei = exp2_f(ai), Ef = exp2_f(af), Eg = exp2_f(ag), Eo = exp2_f(ao);
        const float pf  = 1.0f + Ef;
        const float P   = (1.0f + Ei) * (1.0f + Eg);
        const float den = pf * P;
        const float num = __builtin_fmaf(cc, P, (Eg - 1.0f) * pf);
        cc = num * rcp_f(den);
        const float ac = fminf(cc * L2E2, 80.0f);
        const float Ec = exp2_f(ac);
        const float h  = (Ec - 1.0f) * rcp_f((1.0f + Eo) * (1.0f + Ec));
        return f2h(h);
    };

#define REDIST(G, PG)                                                                  \
    {                                                                                  \
        const float e00 = bh ? acc[G][1] : acc[G][0];                                  \
        const float e02 = bh ? acc[G][3] : acc[G][2];                                  \
        const float v1  = qodd ? e02 : e00;                                            \
        const float v2  = qodd ? e00 : e02;                                            \
        const float r1  = bperm(srcl, v1);                                             \
        const float r2  = bperm(srcl, v2);                                             \
        PG = useb1 ? r1 : r2;                                                          \
    }

#define STEP(T, CUR, NXT, STAGEOK)                                                     \
    {                                                                                  \
        const int tc = (T) & (CHUNK - 1);                                              \
        if (STAGEOK && tc == 0) {                                                      \
            {   /* BT*CHUNK/4 = 512 float4 loads, one per thread */                    \
                const int r = tid >> 6, c4 = tid & 63;                                 \
                const float4 q = ((const float4*)x)[((b0 + r) * TT + (T)) / 4 + c4];   \
                *(float4*)&xs[r * XST + c4 * 4] = q;                                   \
            }                                                                          \
            __syncthreads();   /* also covers hb zero/plant at t==0 */                 \
        }                                                                              \
        H8 a0, a1;                                                                     \
        a0.v = *(const half8*)&(CUR)[l16 * HST + quad * 8];                            \
        a1.v = *(const half8*)&(CUR)[l16 * HST + 32 + quad * 8];                       \
        if (STAGEOK && tc == 0) {                                                      \
            /* chunk-boundary: LDS x-slot stale; patch regs (uniform, 4/1024 steps) */ \
            const float xv = (l16 < BT) ? xs[l16 * XST] : 0.0f;                        \
            const unsigned int pk = 0x3c000000u | (unsigned int)f2h(xv);               \
            a1.i[1] = q2 ? pk : a1.i[1];                                               \
            a1.i[2] = q2 ? 0x00003c00u : a1.i[2];                                      \
        }                                                                              \
        float xnext = 0.0f;                                                            \
        if (xw) xnext = xs[lane * XST + ((tc + 1) & (CHUNK - 1))];                     \
        f32x4 acc[4];                                                                  \
        _Pragma("unroll")                                                              \
        for (int t4 = 0; t4 < 4; ++t4) {                                               \
            acc[t4] = __builtin_amdgcn_mfma_f32_16x16x32_f16(a0.v, bw[t4][0].v, kZ, 0, 0, 0);       \
            acc[t4] = __builtin_amdgcn_mfma_f32_16x16x32_f16(a1.v, bw[t4][1].v, acc[t4], 0, 0, 0);  \
        }                                                                              \
        float p0, p1, p2, p3;                                                          \
        REDIST(0, p0) REDIST(1, p1) REDIST(2, p2) REDIST(3, p3)                        \
        const unsigned short hv = cell(p0, p1, p2, p3, c);                             \
        if (jv) (NXT)[bmine * HST + j] = hv;   /* j>=50 lanes must not clobber k-slots */ \
        if (xw) (NXT)[lane * HST + 50] = f2h(xnext);  /* stale at chunk end: patched */\
        __syncthreads();                                                               \
    }

    for (int t = 0; t < TT; t += 2) {
        STEP(t,     hb[0], hb[1], true);
        STEP(t + 1, hb[1], hb[0], false);
    }
#undef STEP
#undef REDIST
    unsigned short* cur = hb[0];   // final h1

    // ---- LSTM2: one cell step from zero state, input = h1 (waves bh==0 only) ----
    if (bh == 0) {
        H8 bw2[4][2];
        float b2[4];
        #pragma unroll
        for (int t4 = 0; t4 < 4; ++t4) {
            const float sc = (t4 == 2) ? L2E2 : -L2E;
            const int row = t4 * HH + j;
            #pragma unroll
            for (int kk = 0; kk < 2; ++kk)
                #pragma unroll
                for (int e = 0; e < 8; ++e) {
                    const int k = kk * 32 + quad * 8 + e;
                    const float v = (jv && k < HH) ? wih2[row * HH + k] * sc : 0.0f;
                    bw2[t4][kk].h[e] = (_Float16)v;
                }
            b2[t4] = jv ? (bih2[row] + bhh2[row]) * sc : 0.0f;
        }
        H8 a0, a1;   // rows 8-15 of cur zero (planted 1.0s hit k=51,52 where bw2=0)
        a0.v = *(const half8*)&cur[l16 * HST + quad * 8];
        a1.v = *(const half8*)&cur[l16 * HST + 32 + quad * 8];
        f32x4 acc2[4];
        #pragma unroll
        for (int t4 = 0; t4 < 4; ++t4) {
            const f32x4 cb = {b2[t4], b2[t4], b2[t4], b2[t4]};
            acc2[t4] = __builtin_amdgcn_mfma_f32_16x16x32_f16(a0.v, bw2[t4][0].v, cb, 0, 0, 0);
            acc2[t4] = __builtin_amdgcn_mfma_f32_16x16x32_f16(a1.v, bw2[t4][1].v, acc2[t4], 0, 0, 0);
        }
        #pragma unroll
        for (int r = 0; r < 4; ++r) {
            const int b = quad * 4 + r;          // valid rows 0..7 (quads 0,1)
            const float ig = sigm_n(acc2[0][r]);
            const float gg = tanh_p(acc2[2][r]);
            const float og = sigm_n(acc2[3][r]);
            const float cc = ig * gg;            // f*c0 term vanishes (c0 = 0)
            const float h2 = og * tanh_p(cc * L2E2);
            if (b < BT && jv) h2s[b * 52 + j] = h2;
        }
    }
    __syncthreads();

    // ---- FC: out[b] = h2[b] . fcW + fcb  (8 batches x 16 lanes) ----
    if (tid < BT * 16) {
        const int b = tid >> 4, l = tid & 15;
        float p = 0.f;
        for (int jj = l; jj < HH; jj += 16)
            p = __builtin_fmaf(h2s[b * 52 + jj], fcw[jj], p);
        #pragma unroll
        for (int off = 8; off > 0; off >>= 1) p += __shfl_xor(p, off, 16);
        if (l == 0) out[b0 + b] = p + fcb[0];
    }
}

extern "C" void kernel_launch(void* const* d_in, const int* in_sizes, int n_in,
                              void* d_out, int out_size, void* d_ws, size_t ws_size,
                              hipStream_t stream) {
    lstm_mfma_kernel<<<NB, 512, 0, stream>>>(
        (const float*)d_in[0],                         // x
        (const float*)d_in[1], (const float*)d_in[2],  // lstm1 Wih, Whh
        (const float*)d_in[3], (const float*)d_in[4],  // lstm1 bih, bhh
        (const float*)d_in[5],                         // lstm2 Wih
        (const float*)d_in[7], (const float*)d_in[8],  // lstm2 bih, bhh
        (const float*)d_in[9], (const float*)d_in[10], // fc W, b
        (float*)d_out);
}

// Round 7
// 507.703 us; speedup vs baseline: 1.9853x; 1.0180x over previous
//
#include <hip/hip_runtime.h>

#define HH 50
#define TT 1024
#define BT 8             // batch tile per block (half an MFMA M)
#define NB (2048 / BT)   // 256 blocks -> 1 per CU, all CUs active
#define CHUNK 256        // x staging chunk (timesteps)
#define XST 260          // x LDS row stride (floats)
#define HST 72           // h LDS row stride (f16 elems)

typedef _Float16 half8 __attribute__((ext_vector_type(8)));
typedef float f32x4 __attribute__((ext_vector_type(4)));

union H8 { half8 v; _Float16 h[8]; unsigned short u[8]; unsigned int i[4]; };

__device__ __forceinline__ float rcp_f(float x) { return __builtin_amdgcn_rcpf(x); }

#if __has_builtin(__builtin_amdgcn_exp2f)
__device__ __forceinline__ float exp2_f(float x) { return __builtin_amdgcn_exp2f(x); }
#else
__device__ __forceinline__ float exp2_f(float x) { return __expf(0.6931471805599453f * x); }
#endif

#define L2E   1.4426950408889634f
#define L2E2  2.8853900817779268f

__device__ __forceinline__ float sigm_n(float a) {   // sigmoid(x), a = -x*log2e
    return rcp_f(1.0f + exp2_f(a));
}
__device__ __forceinline__ float tanh_p(float a) {   // tanh(x), a = 2x*log2e
    return __builtin_fmaf(-2.0f, rcp_f(1.0f + exp2_f(a)), 1.0f);
}
__device__ __forceinline__ unsigned short f2h(float f) {
    return __builtin_bit_cast(unsigned short, (_Float16)f);
}
__device__ __forceinline__ float bperm(int addr, float v) {
    return __builtin_bit_cast(float,
        __builtin_amdgcn_ds_bpermute(addr, __builtin_bit_cast(int, v)));
}

__global__ __launch_bounds__(256) void lstm_mfma_kernel(
    const float* __restrict__ x,
    const float* __restrict__ wih1, const float* __restrict__ whh1,
    const float* __restrict__ bih1, const float* __restrict__ bhh1,
    const float* __restrict__ wih2,
    const float* __restrict__ bih2, const float* __restrict__ bhh2,
    const float* __restrict__ fcw,  const float* __restrict__ fcb,
    float* __restrict__ out)
{
    __shared__ float xs[BT * XST];                           // 8.3 KB
    __shared__ __align__(16) unsigned short hb[2][16 * HST]; // 4.6 KB (rows 8-15 stay 0)
    __shared__ float h2s[BT * 52];                           // 1.7 KB

    const int tid  = threadIdx.x;
    const int wv   = tid >> 6;        // 0..3 = j-slice
    const int js   = wv;
    const int lane = tid & 63;
    const int l16  = lane & 15;
    const int quad = lane >> 4;
    const int j    = js * 16 + l16;   // padded gate sub-index 0..63
    const bool jv  = (j < HH);
    const bool q2  = (quad == 2);
    const int b0   = blockIdx.x * BT;
    // 2-cells-per-lane redistribution (no wave duplication).
    // acc[G][r] at lane (quad,l16) = gate G pre-act of (batch quad*4+r, col l16);
    // valid batches 0..7 live in quads 0,1.  Ownership after redistribution:
    //   q0: rows 0,1 (own regs 0,1)   q1: rows 4,5 (own regs 0,1)
    //   q2: rows 2,3 (bperm q0 regs 2,3)   q3: rows 6,7 (bperm q1 regs 2,3)
    const int  srcl  = (((quad & 1) << 4) + l16) * 4;  // bpermute byte addr (q2->q0, q3->q1)
    const bool qlow  = (quad < 2);
    const int  bm0   = ((quad & 1) << 2) + ((quad >> 1) << 1);   // first owned row

    // ---- persistent per-lane weights: Whh B-frags (f16, gate-folded scale) ----
    // K layout: k=0..49 Whh; k=50 <- Wih (x slot); k=51 <- bias_hi; k=52 <- bias_lo
    H8 bw[4][2];
    #pragma unroll
    for (int t4 = 0; t4 < 4; ++t4) {
        const float sc = (t4 == 2) ? L2E2 : -L2E;
        const int row = t4 * HH + j;
        #pragma unroll
        for (int kk = 0; kk < 2; ++kk)
            #pragma unroll
            for (int e = 0; e < 8; ++e) {
                const int k = kk * 32 + quad * 8 + e;
                const float v = (jv && k < HH) ? whh1[row * HH + k] * sc : 0.0f;
                bw[t4][kk].h[e] = (_Float16)v;
            }
        if (q2) {
            const float bsc = jv ? (bih1[row] + bhh1[row]) * sc : 0.0f;
            const _Float16 bhi = (_Float16)bsc;
            bw[t4][1].h[2] = (_Float16)(jv ? wih1[row] * sc : 0.0f); // k=50
            bw[t4][1].h[3] = bhi;                                    // k=51
            bw[t4][1].h[4] = (_Float16)(bsc - (float)bhi);           // k=52
        }
    }

    // zero h buffers with 1.0 planted at A-slots k=51,52 (race-free single pass)
    for (int i = tid; i < 2 * 16 * HST; i += 256) {
        const int col = i % HST;
        ((unsigned short*)hb)[i] = (col == 51 || col == 52) ? 0x3c00 : 0;
    }

    float c0 = 0.f, c1 = 0.f;            // two cells per lane (rows bm0, bm0+1)
    const f32x4 kZ = {0.f, 0.f, 0.f, 0.f};
    const bool xw = (wv == 0) && (lane < BT);   // x-slot writer lanes (row = lane)

    // fused cell: 7 trans (5 exp2 + 2 rcp)
    auto cell = [&](float ai, float af, float ag, float ao, float& cc) -> unsigned short {
        const float Ei = exp2_f(ai), Ef = exp2_f(af), Eg = exp2_f(ag), Eo = exp2_f(ao);
        const float pf  = 1.0f + Ef;
        const float P   = (1.0f + Ei) * (1.0f + Eg);
        const float den = pf * P;
        const float num = __builtin_fmaf(cc, P, (Eg - 1.0f) * pf);
        cc = num * rcp_f(den);
        const float ac = fminf(cc * L2E2, 80.0f);
        const float Ec = exp2_f(ac);
        const float h  = (Ec - 1.0f) * rcp_f((1.0f + Eo) * (1.0f + Ec));
        return f2h(h);
    };

#define REDIST(G, P0, P1)                                                              \
    {                                                                                  \
        const float r1 = bperm(srcl, acc[G][2]);                                       \
        const float r2 = bperm(srcl, acc[G][3]);                                       \
        P0 = qlow ? acc[G][0] : r1;                                                    \
        P1 = qlow ? acc[G][1] : r2;                                                    \
    }

#define STEP(T, CUR, NXT, STAGEOK)                                                     \
    {                                                                                  \
        const int tc = (T) & (CHUNK - 1);                                              \
        if (STAGEOK && tc == 0) {                                                      \
            for (int i = tid; i < BT * (CHUNK / 4); i += 256) {                        \
                const int r = i >> 6, c4 = i & 63;                                     \
                const float4 q = ((const float4*)x)[((b0 + r) * TT + (T)) / 4 + c4];   \
                *(float4*)&xs[r * XST + c4 * 4] = q;                                   \
            }                                                                          \
            __syncthreads();   /* also covers hb zero/plant at t==0 */                 \
        }                                                                              \
        H8 a0, a1;                                                                     \
        a0.v = *(const half8*)&(CUR)[l16 * HST + quad * 8];                            \
        a1.v = *(const half8*)&(CUR)[l16 * HST + 32 + quad * 8];                       \
        if (STAGEOK && tc == 0) {                                                      \
            /* chunk-boundary: LDS x-slot stale; patch regs (uniform, 4/1024 steps) */ \
            const float xv = (l16 < BT) ? xs[l16 * XST] : 0.0f;                        \
            const unsigned int pk = 0x3c000000u | (unsigned int)f2h(xv);               \
            a1.i[1] = q2 ? pk : a1.i[1];                                               \
            a1.i[2] = q2 ? 0x00003c00u : a1.i[2];                                      \
        }                                                                              \
        float xnext = 0.0f;                                                            \
        if (xw) xnext = xs[lane * XST + ((tc + 1) & (CHUNK - 1))];                     \
        f32x4 acc[4];                                                                  \
        _Pragma("unroll")                                                              \
        for (int t4 = 0; t4 < 4; ++t4) {                                               \
            acc[t4] = __builtin_amdgcn_mfma_f32_16x16x32_f16(a0.v, bw[t4][0].v, kZ, 0, 0, 0);       \
            acc[t4] = __builtin_amdgcn_mfma_f32_16x16x32_f16(a1.v, bw[t4][1].v, acc[t4], 0, 0, 0);  \
        }                                                                              \
        float pi0, pi1, pf0, pf1, pg0, pg1, po0, po1;                                  \
        REDIST(0, pi0, pi1) REDIST(1, pf0, pf1)                                        \
        REDIST(2, pg0, pg1) REDIST(3, po0, po1)                                        \
        const unsigned short h0 = cell(pi0, pf0, pg0, po0, c0);                        \
        const unsigned short h1 = cell(pi1, pf1, pg1, po1, c1);                        \
        if (jv) {   /* j>=50 lanes must not clobber the planted k-slots */             \
            (NXT)[bm0 * HST + j]       = h0;                                           \
            (NXT)[(bm0 + 1) * HST + j] = h1;                                           \
        }                                                                              \
        if (xw) (NXT)[lane * HST + 50] = f2h(xnext);  /* stale at chunk end: patched */\
        __syncthreads();                                                               \
    }

    for (int t = 0; t < TT; t += 2) {
        STEP(t,     hb[0], hb[1], true);
        STEP(t + 1, hb[1], hb[0], false);
    }
#undef STEP
#undef REDIST
    unsigned short* cur = hb[0];   // final h1

    // ---- LSTM2: one cell step from zero state, input = h1 ----
    {
        H8 bw2[4][2];
        float b2[4];
        #pragma unroll
        for (int t4 = 0; t4 < 4; ++t4) {
            const float sc = (t4 == 2) ? L2E2 : -L2E;
            const int row = t4 * HH + j;
            #pragma unroll
            for (int kk = 0; kk < 2; ++kk)
                #pragma unroll
                for (int e = 0; e < 8; ++e) {
                    const int k = kk * 32 + quad * 8 + e;
                    const float v = (jv && k < HH) ? wih2[row * HH + k] * sc : 0.0f;
                    bw2[t4][kk].h[e] = (_Float16)v;
                }
            b2[t4] = jv ? (bih2[row] + bhh2[row]) * sc : 0.0f;
        }
        H8 a0, a1;   // rows 8-15 of cur zero (planted 1.0s hit k=51,52 where bw2=0)
        a0.v = *(const half8*)&cur[l16 * HST + quad * 8];
        a1.v = *(const half8*)&cur[l16 * HST + 32 + quad * 8];
        f32x4 acc2[4];
        #pragma unroll
        for (int t4 = 0; t4 < 4; ++t4) {
            const f32x4 cb = {b2[t4], b2[t4], b2[t4], b2[t4]};
            acc2[t4] = __builtin_amdgcn_mfma_f32_16x16x32_f16(a0.v, bw2[t4][0].v, cb, 0, 0, 0);
            acc2[t4] = __builtin_amdgcn_mfma_f32_16x16x32_f16(a1.v, bw2[t4][1].v, acc2[t4], 0, 0, 0);
        }
        #pragma unroll
        for (int r = 0; r < 4; ++r) {
            const int b = quad * 4 + r;          // valid rows 0..7 (quads 0,1)
            const float ig = sigm_n(acc2[0][r]);
            const float gg = tanh_p(acc2[2][r]);
            const float og = sigm_n(acc2[3][r]);
            const float cc = ig * gg;            // f*c0 term vanishes (c0 = 0)
            const float h2 = og * tanh_p(cc * L2E2);
            if (b < BT && jv) h2s[b * 52 + j] = h2;
        }
    }
    __syncthreads();

    // ---- FC: out[b] = h2[b] . fcW + fcb  (8 batches x 16 lanes) ----
    if (tid < BT * 16) {
        const int b = tid >> 4, l = tid & 15;
        float p = 0.f;
        for (int jj = l; jj < HH; jj += 16)
            p = __builtin_fmaf(h2s[b * 52 + jj], fcw[jj], p);
        #pragma unroll
        for (int off = 8; off > 0; off >>= 1) p += __shfl_xor(p, off, 16);
        if (l == 0) out[b0 + b] = p + fcb[0];
    }
}

extern "C" void kernel_launch(void* const* d_in, const int* in_sizes, int n_in,
                              void* d_out, int out_size, void* d_ws, size_t ws_size,
                              hipStream_t stream) {
    lstm_mfma_kernel<<<NB, 256, 0, stream>>>(
        (const float*)d_in[0],                         // x
        (const float*)d_in[1], (const float*)d_in[2],  // lstm1 Wih, Whh
        (const float*)d_in[3], (const float*)d_in[4],  // lstm1 bih, bhh
        (const float*)d_in[5],                         // lstm2 Wih
        (const float*)d_in[7], (const float*)d_in[8],  // lstm2 bih, bhh
        (const float*)d_in[9], (const float*)d_in[10], // fc W, b
        (float*)d_out);
}